// Round 10
// baseline (185.090 us; speedup 1.0000x reference)
//
#include <hip/hip_runtime.h>
#include <math.h>

namespace {

constexpr int kH = 256, kOut = 128;
constexpr int kNV = 65536;
constexpr float kEps = 1e-5f;

typedef __attribute__((ext_vector_type(8))) short bf16x8;
typedef __attribute__((ext_vector_type(4))) float f32x4;
typedef unsigned int u32;

__device__ inline short f2bf(float f) {
  union { float f; u32 u; } v; v.f = f;
  u32 r = v.u + 0x7fffu + ((v.u >> 16) & 1u);
  return (short)(r >> 16);
}
__device__ inline float bf2f(short s) {
  union { float f; u32 u; } v; v.u = ((u32)(unsigned short)s) << 16; return v.f;
}

// ---- KP: pack Wg/W1/W2 into MFMA B-fragment order; wgab = Wg@[a1|a2] in
//          bf16 B-fragment order; zero stats. (unchanged)
__global__ __launch_bounds__(256) void kpack(
    const float* __restrict__ Wg, const float* __restrict__ W1,
    const float* __restrict__ W2, const float* __restrict__ a_w,
    short* __restrict__ wgp, short* __restrict__ w1p, short* __restrict__ w2p,
    short* __restrict__ wgab, float* __restrict__ st)
{
  const int bid = blockIdx.x, t = threadIdx.x;
  if (bid >= 152) {
    const int b = bid - 152;
    if (t < 144) {
      const int col = t & 1, k = b * 72 + (t >> 1);
      if (k < 576) {
        const float* rowp = Wg + (size_t)k * 256;
        const float* ap = a_w + col * 256;
        float s0 = 0.f, s1 = 0.f, s2 = 0.f, s3 = 0.f;
        for (int c = 0; c < 256; c += 4) {
          s0 = fmaf(rowp[c+0], ap[c+0], s0);
          s1 = fmaf(rowp[c+1], ap[c+1], s1);
          s2 = fmaf(rowp[c+2], ap[c+2], s2);
          s3 = fmaf(rowp[c+3], ap[c+3], s3);
        }
        const int ks = k >> 5, r = k & 31, hq = r >> 3, e = r & 7;
        wgab[((ks*2 + col)*4 + hq)*8 + e] = f2bf((s0 + s1) + (s2 + s3));
      }
    }
    return;
  }
  if (bid == 0) {
#pragma unroll
    for (int i = 0; i < 6; ++i) st[i*256 + t] = 0.f;
  }
  const int uid = bid * 256 + t;
  const float* src; short* dst; int N; int u;
  if (uid < 18432)            { src = Wg; dst = wgp; N = 256; u = uid; }
  else if (uid < 34816)       { src = W1; dst = w1p; N = 256; u = uid - 18432; }
  else if (uid < 38912)       { src = W2; dst = w2p; N = 128; u = uid - 34816; }
  else return;
  const int lane = u & 63, ctkt = u >> 6;
  const int nct = N >> 4;
  const int kt = ctkt / nct, ct = ctkt % nct;
  const int row = kt * 32 + (lane >> 4) * 8;
  const int col = ct * 16 + (lane & 15);
  bf16x8 ov;
#pragma unroll
  for (int e = 0; e < 8; ++e) ov[e] = f2bf(src[(size_t)(row + e) * N + col]);
  *reinterpret_cast<bf16x8*>(dst + (size_t)u * 8) = ov;
}

// ---- K1: 32-row tile; depth-1 B prefetch (r6 version, proven) -------------
__global__ __launch_bounds__(256, 4) void k1_encode(
    const float* __restrict__ obs, const float* __restrict__ hin,
    const float* __restrict__ Ws, const float* __restrict__ bs,
    const float* __restrict__ Wv, const float* __restrict__ bv,
    const short* __restrict__ wgp, const short* __restrict__ wgab,
    short* __restrict__ hpack, float* __restrict__ ha1, float* __restrict__ ha2)
{
  __shared__ __align__(16) short comb[32][584];
  __shared__ float obs_s[32][4];
  const int t = threadIdx.x;
  const int xcd = blockIdx.x & 7, ib = blockIdx.x >> 3;
  const int workid = xcd * 256 + ib;
  const int r0 = workid * 32;

  if (t < 128) obs_s[t >> 2][t & 3] = obs[(size_t)(r0 + (t >> 2)) * 5 + 1 + (t & 3)];
#pragma unroll
  for (int jj = 0; jj < 2; ++jj) {
    const int f = jj * 1024 + t * 4;
    const int row = f >> 6, c = f & 63;
    const float4 v = *reinterpret_cast<const float4*>(hin + (size_t)r0 * 64 + f);
    short4 o;
    o.x = f2bf(v.x); o.y = f2bf(v.y); o.z = f2bf(v.z); o.w = f2bf(v.w);
    *reinterpret_cast<short4*>(&comb[row][512 + c]) = o;
  }
  const float ws0 = Ws[t], ws1 = Ws[256 + t], bsv = bs[t];
  const float wv0 = Wv[t], wv1 = Wv[256 + t], bvv = bv[t];
  __syncthreads();
  for (int r = 0; r < 32; ++r) {
    const float o1 = obs_s[r][0], o2 = obs_s[r][1], o3 = obs_s[r][2], o4 = obs_s[r][3];
    const float sv = fmaf(o2, ws1, fmaf(o1, ws0, bsv));
    comb[r][t] = f2bf(fmaxf(sv, 0.f));
    const float vv = fmaf(o4, wv1, fmaf(o3, wv0, bvv));
    comb[r][256 + t] = f2bf(fmaxf(vv, 0.f));
  }
  __syncthreads();

  const int w = t >> 6, lane = t & 63, lo = lane & 15, hq = lane >> 4;
  f32x4 acc[2][4];
  f32x4 accE[2];
#pragma unroll
  for (int rt = 0; rt < 2; ++rt) {
    accE[rt] = (f32x4){0.f, 0.f, 0.f, 0.f};
#pragma unroll
    for (int ct = 0; ct < 4; ++ct) acc[rt][ct] = (f32x4){0.f, 0.f, 0.f, 0.f};
  }

  const short* wB = wgp + ((size_t)(w*4)*64 + lane)*8;
  bf16x8 bb[4];
#pragma unroll
  for (int ct = 0; ct < 4; ++ct)
    bb[ct] = *reinterpret_cast<const bf16x8*>(wB + ct*512);

#pragma unroll
  for (int ks = 0; ks < 18; ++ks) {
    bf16x8 bn[4];
    if (ks < 17) {
#pragma unroll
      for (int ct = 0; ct < 4; ++ct)
        bn[ct] = *reinterpret_cast<const bf16x8*>(wB + (ks+1)*8192 + ct*512);
    }
    bf16x8 a[2];
#pragma unroll
    for (int rt = 0; rt < 2; ++rt)
      a[rt] = *reinterpret_cast<const bf16x8*>(&comb[rt*16 + lo][ks*32 + hq*8]);
#pragma unroll
    for (int rt = 0; rt < 2; ++rt)
#pragma unroll
      for (int ct = 0; ct < 4; ++ct)
        acc[rt][ct] = __builtin_amdgcn_mfma_f32_16x16x32_bf16(a[rt], bb[ct], acc[rt][ct], 0, 0, 0);
    if (w == 0) {
      bf16x8 be;
      if (lo < 2)
        be = *reinterpret_cast<const bf16x8*>(wgab + ((ks*2 + lo)*4 + hq)*8);
      else
        be = (bf16x8){0,0,0,0,0,0,0,0};
#pragma unroll
      for (int rt = 0; rt < 2; ++rt)
        accE[rt] = __builtin_amdgcn_mfma_f32_16x16x32_bf16(a[rt], be, accE[rt], 0, 0, 0);
    }
    if (ks < 17) {
#pragma unroll
      for (int ct = 0; ct < 4; ++ct) bb[ct] = bn[ct];
    }
  }
  if (w == 0 && lo < 2) {
    float* dst = (lo == 0) ? ha1 : ha2;
#pragma unroll
    for (int rt = 0; rt < 2; ++rt)
#pragma unroll
      for (int q = 0; q < 4; ++q)
        dst[r0 + rt*16 + hq*4 + q] = accE[rt][q];
  }
  __syncthreads();

  short* pimg = reinterpret_cast<short*>(&comb[0][0]);
#pragma unroll
  for (int rt = 0; rt < 2; ++rt)
#pragma unroll
    for (int ct = 0; ct < 4; ++ct) {
      const int base = (((w*4 + ct)*64) + (rt*2 + (hq>>1))*16 + lo)*8 + (hq&1)*4;
      short4 val;
      val.x = f2bf(acc[rt][ct][0]); val.y = f2bf(acc[rt][ct][1]);
      val.z = f2bf(acc[rt][ct][2]); val.w = f2bf(acc[rt][ct][3]);
      *reinterpret_cast<short4*>(pimg + base) = val;
    }
  __syncthreads();

  short* dst = hpack + (size_t)workid * 8192;
#pragma unroll
  for (int j = 0; j < 4; ++j)
    *reinterpret_cast<bf16x8*>(dst + j*2048 + t*8) =
        *reinterpret_cast<const bf16x8*>(pimg + j*2048 + t*8);
}

// ---- K23: 32-row tile, 5 blocks/CU. softmax + h'=att@h + y=[h'|se]@W1
//           + BN1 sums. depth-1 prefetch, no setprio. ----------------------
__global__ __launch_bounds__(256, 5) void k23_attn_fc1(
    const float* __restrict__ ha1g, const float* __restrict__ ha2g,
    const short* __restrict__ hpack, const float* __restrict__ obs,
    const float* __restrict__ Ws, const float* __restrict__ bs,
    const short* __restrict__ w1p, short* __restrict__ y, float* __restrict__ st)
{
  __shared__ __align__(16) short attimg[32][264];  // att -> h' -> se -> y tile
  __shared__ float ws_s[768];
  __shared__ float ha2_s[256];
  __shared__ float ha1_s[32], rd_s[32];
  __shared__ float red[8][32];
  __shared__ float obs_s[32][2];
  const int t = threadIdx.x;
  const int xcd = blockIdx.x & 7, ib = blockIdx.x >> 3;
  const int workid = xcd * 256 + ib;               // 0..2047, XCD-contiguous
  const int r0 = workid * 32;
  const int n = r0 >> 8;

  ws_s[t] = Ws[t]; ws_s[256 + t] = Ws[256 + t]; ws_s[512 + t] = bs[t];
  ha2_s[t] = ha2g[n*256 + t];
  if (t < 32) ha1_s[t] = ha1g[r0 + t];
  if (t < 64) obs_s[t >> 1][t & 1] = obs[(size_t)(r0 + (t >> 1)) * 5 + 1 + (t & 1)];
  __syncthreads();

  // single-pass softmax numerator: 8 threads/row, 32 cols each
  const int rr = t & 31, seg = t >> 5;
  {
    const float a1 = ha1_s[rr];
    float sum = 0.f;
    for (int c8 = 0; c8 < 4; ++c8) {
      bf16x8 pk;
#pragma unroll
      for (int e = 0; e < 8; ++e) {
        float x = a1 + ha2_s[seg*32 + c8*8 + e];
        x = fmaxf(x, 0.01f * x);          // leaky_relu
        const float ev = __expf(x);
        sum += ev;
        pk[e] = f2bf(ev);
      }
      *reinterpret_cast<bf16x8*>(&attimg[rr][seg*32 + c8*8]) = pk;
    }
    red[seg][rr] = sum;
  }
  __syncthreads();
  if (t < 32) {
    const float s = (red[0][t] + red[1][t]) + (red[2][t] + red[3][t])
                  + (red[4][t] + red[5][t]) + (red[6][t] + red[7][t]);
    rd_s[t] = 1.f / s;
  }
  __syncthreads();

  const int w = t >> 6, lane = t & 63, lo = lane & 15, hq = lane >> 4;
  f32x4 acc[2][4];
#pragma unroll
  for (int rt = 0; rt < 2; ++rt)
#pragma unroll
    for (int ct = 0; ct < 4; ++ct) acc[rt][ct] = (f32x4){0.f, 0.f, 0.f, 0.f};

  // MFMA1: h' = att @ h (B from hpack, depth-1 prefetch)
  {
    const short* bB = hpack + (size_t)n*65536 + ((size_t)(w*4)*64 + lane)*8;
    bf16x8 bb[4];
#pragma unroll
    for (int ct = 0; ct < 4; ++ct) bb[ct] = *reinterpret_cast<const bf16x8*>(bB + ct*512);
    for (int ks = 0; ks < 8; ++ks) {
      bf16x8 bn[4];
      if (ks < 7) {
#pragma unroll
        for (int ct = 0; ct < 4; ++ct)
          bn[ct] = *reinterpret_cast<const bf16x8*>(bB + (ks+1)*8192 + ct*512);
      }
      bf16x8 a[2];
#pragma unroll
      for (int rt = 0; rt < 2; ++rt)
        a[rt] = *reinterpret_cast<const bf16x8*>(&attimg[rt*16 + lo][ks*32 + hq*8]);
#pragma unroll
      for (int rt = 0; rt < 2; ++rt)
#pragma unroll
        for (int ct = 0; ct < 4; ++ct)
          acc[rt][ct] = __builtin_amdgcn_mfma_f32_16x16x32_bf16(a[rt], bb[ct], acc[rt][ct], 0, 0, 0);
      if (ks < 7) {
#pragma unroll
        for (int ct = 0; ct < 4; ++ct) bb[ct] = bn[ct];
      }
    }
  }
  __syncthreads();

  // scaled h' into attimg
#pragma unroll
  for (int rt = 0; rt < 2; ++rt)
#pragma unroll
    for (int q = 0; q < 4; ++q) {
      const int row = rt*16 + hq*4 + q;
      const float sc = rd_s[row];
#pragma unroll
      for (int ct = 0; ct < 4; ++ct)
        attimg[row][w*64 + ct*16 + lo] = f2bf(acc[rt][ct][q] * sc);
    }
  __syncthreads();

  // MFMA2a: y += h' @ W1[0:256] (depth-1)
  f32x4 accY[2][4];
#pragma unroll
  for (int rt = 0; rt < 2; ++rt)
#pragma unroll
    for (int ct = 0; ct < 4; ++ct) accY[rt][ct] = (f32x4){0.f, 0.f, 0.f, 0.f};
  const short* w1B = w1p + ((size_t)(w*4)*64 + lane)*8;
  {
    bf16x8 bb[4];
#pragma unroll
    for (int ct = 0; ct < 4; ++ct) bb[ct] = *reinterpret_cast<const bf16x8*>(w1B + ct*512);
    for (int ks = 0; ks < 8; ++ks) {
      bf16x8 bn[4];
      if (ks < 7) {
#pragma unroll
        for (int ct = 0; ct < 4; ++ct)
          bn[ct] = *reinterpret_cast<const bf16x8*>(w1B + (ks+1)*8192 + ct*512);
      }
      bf16x8 a[2];
#pragma unroll
      for (int rt = 0; rt < 2; ++rt)
        a[rt] = *reinterpret_cast<const bf16x8*>(&attimg[rt*16 + lo][ks*32 + hq*8]);
#pragma unroll
      for (int rt = 0; rt < 2; ++rt)
#pragma unroll
        for (int ct = 0; ct < 4; ++ct)
          accY[rt][ct] = __builtin_amdgcn_mfma_f32_16x16x32_bf16(a[rt], bb[ct], accY[rt][ct], 0, 0, 0);
      if (ks < 7) {
#pragma unroll
        for (int ct = 0; ct < 4; ++ct) bb[ct] = bn[ct];
      }
    }
  }
  __syncthreads();

  // build se into attimg (overwrites h')
  {
    const float o1 = obs_s[rr][0], o2 = obs_s[rr][1];
    for (int c8 = 0; c8 < 4; ++c8) {
      const int c = seg*32 + c8*8;
      bf16x8 pk;
#pragma unroll
      for (int e = 0; e < 8; ++e) {
        const float sv = fmaf(o2, ws_s[256 + c + e], fmaf(o1, ws_s[c + e], ws_s[512 + c + e]));
        pk[e] = f2bf(fmaxf(sv, 0.f));
      }
      *reinterpret_cast<bf16x8*>(&attimg[rr][c]) = pk;
    }
  }
  __syncthreads();

  // MFMA2b: y += se @ W1[256:512] (depth-1)
  {
    bf16x8 bb[4];
#pragma unroll
    for (int ct = 0; ct < 4; ++ct)
      bb[ct] = *reinterpret_cast<const bf16x8*>(w1B + 8*8192 + ct*512);
    for (int ks = 0; ks < 8; ++ks) {
      bf16x8 bn[4];
      if (ks < 7) {
#pragma unroll
        for (int ct = 0; ct < 4; ++ct)
          bn[ct] = *reinterpret_cast<const bf16x8*>(w1B + (ks+9)*8192 + ct*512);
      }
      bf16x8 a[2];
#pragma unroll
      for (int rt = 0; rt < 2; ++rt)
        a[rt] = *reinterpret_cast<const bf16x8*>(&attimg[rt*16 + lo][ks*32 + hq*8]);
#pragma unroll
      for (int rt = 0; rt < 2; ++rt)
#pragma unroll
        for (int ct = 0; ct < 4; ++ct)
          accY[rt][ct] = __builtin_amdgcn_mfma_f32_16x16x32_bf16(a[rt], bb[ct], accY[rt][ct], 0, 0, 0);
      if (ks < 7) {
#pragma unroll
        for (int ct = 0; ct < 4; ++ct) bb[ct] = bn[ct];
      }
    }
  }

  // BN1 partial sums
  float sm[4] = {0,0,0,0}, ssm[4] = {0,0,0,0};
#pragma unroll
  for (int rt = 0; rt < 2; ++rt)
#pragma unroll
    for (int q = 0; q < 4; ++q)
#pragma unroll
      for (int ct = 0; ct < 4; ++ct) {
        const float v = accY[rt][ct][q];
        sm[ct] += v; ssm[ct] += v * v;
      }
#pragma unroll
  for (int off = 16; off < 64; off <<= 1)
#pragma unroll
    for (int ct = 0; ct < 4; ++ct) {
      sm[ct] += __shfl_xor(sm[ct], off);
      ssm[ct] += __shfl_xor(ssm[ct], off);
    }
  if (hq == 0)
#pragma unroll
    for (int ct = 0; ct < 4; ++ct) {
      const int col = w*64 + ct*16 + lo;
      atomicAdd(&st[col], sm[ct]);
      atomicAdd(&st[256 + col], ssm[ct]);
    }
  __syncthreads();

  // y tile into attimg, coalesced store
#pragma unroll
  for (int rt = 0; rt < 2; ++rt)
#pragma unroll
    for (int q = 0; q < 4; ++q) {
      const int row = rt*16 + hq*4 + q;
#pragma unroll
      for (int ct = 0; ct < 4; ++ct)
        attimg[row][w*64 + ct*16 + lo] = f2bf(accY[rt][ct][q]);
    }
  __syncthreads();
  const short* img = &attimg[0][0];
#pragma unroll
  for (int j = 0; j < 4; ++j) {
    const int f = j*2048 + t*8, row = f >> 8, col = f & 255;
    *reinterpret_cast<bf16x8*>(y + (size_t)(r0 + row)*256 + col) =
        *reinterpret_cast<const bf16x8*>(img + row*264 + col);
  }
}

// ---- K5: 32-row tile, 6 blocks/CU. z = relu(bn1(y)) @ W2 + BN2 sums -------
__global__ __launch_bounds__(256, 6) void k5_z(
    const short* __restrict__ y, const short* __restrict__ w2p,
    const float* __restrict__ g1, const float* __restrict__ be1,
    float* __restrict__ st, short* __restrict__ zb)
{
  __shared__ __align__(16) short xs[32][264];
  __shared__ float sc_s[256], sh_s[256];
  const int t = threadIdx.x;
  const int r0 = blockIdx.x * 32;
  {
    const float mean = st[t] * (1.f / kNV);
    const float var  = st[256 + t] * (1.f / kNV) - mean * mean;
    const float sc   = g1[t] / sqrtf(var + kEps);
    sc_s[t] = sc; sh_s[t] = be1[t] - mean * sc;
  }
  __syncthreads();
#pragma unroll
  for (int j = 0; j < 4; ++j) {
    const int f = j*2048 + t*8, row = f >> 8, col = f & 255;
    bf16x8 v = *reinterpret_cast<const bf16x8*>(y + (size_t)(r0 + row)*256 + col);
    bf16x8 ov;
#pragma unroll
    for (int e = 0; e < 8; ++e) {
      const float fv = fmaf(bf2f(v[e]), sc_s[col + e], sh_s[col + e]);
      ov[e] = f2bf(fmaxf(fv, 0.f));
    }
    *reinterpret_cast<bf16x8*>(&xs[row][col]) = ov;
  }
  __syncthreads();

  const int w = t >> 6, lane = t & 63, lo = lane & 15, hq = lane >> 4;
  f32x4 acc[2][2];
#pragma unroll
  for (int rt = 0; rt < 2; ++rt)
#pragma unroll
    for (int ct = 0; ct < 2; ++ct) acc[rt][ct] = (f32x4){0.f, 0.f, 0.f, 0.f};

  {
    const short* w2B = w2p + ((size_t)(w*2)*64 + lane)*8;
    bf16x8 bb[2];
#pragma unroll
    for (int ct = 0; ct < 2; ++ct) bb[ct] = *reinterpret_cast<const bf16x8*>(w2B + ct*512);
    for (int ks = 0; ks < 8; ++ks) {
      bf16x8 bn[2];
      if (ks < 7) {
#pragma unroll
        for (int ct = 0; ct < 2; ++ct)
          bn[ct] = *reinterpret_cast<const bf16x8*>(w2B + (ks+1)*4096 + ct*512);
      }
      bf16x8 a[2];
#pragma unroll
      for (int rt = 0; rt < 2; ++rt)
        a[rt] = *reinterpret_cast<const bf16x8*>(&xs[rt*16 + lo][ks*32 + hq*8]);
#pragma unroll
      for (int rt = 0; rt < 2; ++rt)
#pragma unroll
        for (int ct = 0; ct < 2; ++ct)
          acc[rt][ct] = __builtin_amdgcn_mfma_f32_16x16x32_bf16(a[rt], bb[ct], acc[rt][ct], 0, 0, 0);
      if (ks < 7) {
#pragma unroll
        for (int ct = 0; ct < 2; ++ct) bb[ct] = bn[ct];
      }
    }
  }

  float sm[2] = {0,0}, ssm[2] = {0,0};
#pragma unroll
  for (int rt = 0; rt < 2; ++rt)
#pragma unroll
    for (int q = 0; q < 4; ++q)
#pragma unroll
      for (int ct = 0; ct < 2; ++ct) {
        const float v = acc[rt][ct][q];
        sm[ct] += v; ssm[ct] += v * v;
      }
#pragma unroll
  for (int off = 16; off < 64; off <<= 1)
#pragma unroll
    for (int ct = 0; ct < 2; ++ct) {
      sm[ct] += __shfl_xor(sm[ct], off);
      ssm[ct] += __shfl_xor(ssm[ct], off);
    }
  if (hq == 0)
#pragma unroll
    for (int ct = 0; ct < 2; ++ct) {
      const int col = w*32 + ct*16 + lo;
      atomicAdd(&st[1024 + col], sm[ct]);
      atomicAdd(&st[1152 + col], ssm[ct]);
    }
  __syncthreads();

  short* zimg = reinterpret_cast<short*>(&xs[0][0]);   // stride 136 shorts
#pragma unroll
  for (int rt = 0; rt < 2; ++rt)
#pragma unroll
    for (int q = 0; q < 4; ++q) {
      const int row = rt*16 + hq*4 + q;
#pragma unroll
      for (int ct = 0; ct < 2; ++ct)
        zimg[row*136 + w*32 + ct*16 + lo] = f2bf(acc[rt][ct][q]);
    }
  __syncthreads();
#pragma unroll
  for (int j = 0; j < 2; ++j) {
    const int f = j*2048 + t*8, row = f >> 7, col = f & 127;
    *reinterpret_cast<bf16x8*>(zb + (size_t)(r0 + row)*128 + col) =
        *reinterpret_cast<const bf16x8*>(zimg + row*136 + col);
  }
}

// ---- K7: out = relu(bn2(z)) -- bf16 in, fp32 out ---------------------------
__global__ __launch_bounds__(256) void k7_out(
    const short* __restrict__ zb, const float* __restrict__ st,
    const float* __restrict__ g2, const float* __restrict__ be2,
    float* __restrict__ out)
{
  __shared__ float sc_s[128], sh_s[128];
  const int t = threadIdx.x;
  if (t < 128) {
    const float mean = st[1024 + t] * (1.f / kNV);
    const float var  = st[1152 + t] * (1.f / kNV) - mean * mean;
    const float sc   = g2[t] / sqrtf(var + kEps);
    sc_s[t] = sc; sh_s[t] = be2[t] - mean * sc;
  }
  __syncthreads();
#pragma unroll
  for (int j = 0; j < 2; ++j) {
    const size_t u = (size_t)blockIdx.x * 512 + j*256 + t;
    bf16x8 v = *reinterpret_cast<const bf16x8*>(zb + u*8);
    const int col = ((int)u & 15) * 8;
    float4 r0, r1;
    r0.x = fmaxf(fmaf(bf2f(v[0]), sc_s[col+0], sh_s[col+0]), 0.f);
    r0.y = fmaxf(fmaf(bf2f(v[1]), sc_s[col+1], sh_s[col+1]), 0.f);
    r0.z = fmaxf(fmaf(bf2f(v[2]), sc_s[col+2], sh_s[col+2]), 0.f);
    r0.w = fmaxf(fmaf(bf2f(v[3]), sc_s[col+3], sh_s[col+3]), 0.f);
    r1.x = fmaxf(fmaf(bf2f(v[4]), sc_s[col+4], sh_s[col+4]), 0.f);
    r1.y = fmaxf(fmaf(bf2f(v[5]), sc_s[col+5], sh_s[col+5]), 0.f);
    r1.z = fmaxf(fmaf(bf2f(v[6]), sc_s[col+6], sh_s[col+6]), 0.f);
    r1.w = fmaxf(fmaf(bf2f(v[7]), sc_s[col+7], sh_s[col+7]), 0.f);
    *reinterpret_cast<float4*>(out + u*8)     = r0;
    *reinterpret_cast<float4*>(out + u*8 + 4) = r1;
  }
}

} // namespace

extern "C" void kernel_launch(void* const* d_in, const int* in_sizes, int n_in,
                              void* d_out, int out_size, void* d_ws, size_t ws_size,
                              hipStream_t stream) {
  const float* obs = (const float*)d_in[0];
  const float* hin = (const float*)d_in[1];
  const float* Ws  = (const float*)d_in[2];
  const float* bs  = (const float*)d_in[3];
  const float* Wv  = (const float*)d_in[4];
  const float* bv  = (const float*)d_in[5];
  const float* Wg  = (const float*)d_in[6];
  const float* a_w = (const float*)d_in[7];
  const float* W1  = (const float*)d_in[8];
  // d_in[9] = b1: cancels in batchnorm
  const float* g1  = (const float*)d_in[10];
  const float* be1 = (const float*)d_in[11];
  const float* W2  = (const float*)d_in[12];
  // d_in[13] = b2: cancels in batchnorm
  const float* g2  = (const float*)d_in[14];
  const float* be2 = (const float*)d_in[15];

  char* base = (char*)d_ws;
  short* hpack = (short*)(base);                 // 33.5 MB
  short* y     = (short*)(base + 33554432);      // 33.5 MB
  short* zb    = (short*)(base + 67108864);      // 16.8 MB
  float* ha1   = (float*)(base + 83886080);
  float* ha2   = (float*)(base + 84148224);
  float* st    = (float*)(base + 84410368);
  short* wgp   = (short*)(base + 84416512);
  short* w1p   = (short*)(base + 84711424);
  short* w2p   = (short*)(base + 84973568);
  short* wgab  = (short*)(base + 85039104);
  float* out   = (float*)d_out;

  kpack       <<<160,  256, 0, stream>>>(Wg, W1, W2, a_w, wgp, w1p, w2p, wgab, st);
  k1_encode   <<<2048, 256, 0, stream>>>(obs, hin, Ws, bs, Wv, bv, wgp, wgab, hpack, ha1, ha2);
  k23_attn_fc1<<<2048, 256, 0, stream>>>(ha1, ha2, hpack, obs, Ws, bs, w1p, y, st);
  k5_z        <<<2048, 256, 0, stream>>>(y, w2p, g1, be1, st, zb);
  k7_out      <<<2048, 256, 0, stream>>>(zb, st, g2, be2, out);
}

// Round 11
// 138.696 us; speedup vs baseline: 1.3345x; 1.3345x over previous
//
#include <hip/hip_runtime.h>
#include <math.h>

namespace {

constexpr int kH = 256, kOut = 128;
constexpr int kNV = 65536;
constexpr float kEps = 1e-5f;

typedef __attribute__((ext_vector_type(8))) short bf16x8;
typedef __attribute__((ext_vector_type(4))) float f32x4;
typedef unsigned int u32;

__device__ inline short f2bf(float f) {
  union { float f; u32 u; } v; v.f = f;
  u32 r = v.u + 0x7fffu + ((v.u >> 16) & 1u);
  return (short)(r >> 16);
}
__device__ inline float bf2f(short s) {
  union { float f; u32 u; } v; v.u = ((u32)(unsigned short)s) << 16; return v.f;
}

// ---- KP: pack Wg/W1/W2 into MFMA B-fragment order; wgab = Wg@[a1|a2] in
//          bf16 B-fragment order; zero stats. (r6 verbatim)
__global__ __launch_bounds__(256) void kpack(
    const float* __restrict__ Wg, const float* __restrict__ W1,
    const float* __restrict__ W2, const float* __restrict__ a_w,
    short* __restrict__ wgp, short* __restrict__ w1p, short* __restrict__ w2p,
    short* __restrict__ wgab, float* __restrict__ st)
{
  const int bid = blockIdx.x, t = threadIdx.x;
  if (bid >= 152) {
    const int b = bid - 152;
    if (t < 144) {
      const int col = t & 1, k = b * 72 + (t >> 1);
      if (k < 576) {
        const float* rowp = Wg + (size_t)k * 256;
        const float* ap = a_w + col * 256;
        float s0 = 0.f, s1 = 0.f, s2 = 0.f, s3 = 0.f;
        for (int c = 0; c < 256; c += 4) {
          s0 = fmaf(rowp[c+0], ap[c+0], s0);
          s1 = fmaf(rowp[c+1], ap[c+1], s1);
          s2 = fmaf(rowp[c+2], ap[c+2], s2);
          s3 = fmaf(rowp[c+3], ap[c+3], s3);
        }
        const int ks = k >> 5, r = k & 31, hq = r >> 3, e = r & 7;
        wgab[((ks*2 + col)*4 + hq)*8 + e] = f2bf((s0 + s1) + (s2 + s3));
      }
    }
    return;
  }
  if (bid == 0) {
#pragma unroll
    for (int i = 0; i < 6; ++i) st[i*256 + t] = 0.f;
  }
  const int uid = bid * 256 + t;
  const float* src; short* dst; int N; int u;
  if (uid < 18432)            { src = Wg; dst = wgp; N = 256; u = uid; }
  else if (uid < 34816)       { src = W1; dst = w1p; N = 256; u = uid - 18432; }
  else if (uid < 38912)       { src = W2; dst = w2p; N = 128; u = uid - 34816; }
  else return;
  const int lane = u & 63, ctkt = u >> 6;
  const int nct = N >> 4;
  const int kt = ctkt / nct, ct = ctkt % nct;
  const int row = kt * 32 + (lane >> 4) * 8;
  const int col = ct * 16 + (lane & 15);
  bf16x8 ov;
#pragma unroll
  for (int e = 0; e < 8; ++e) ov[e] = f2bf(src[(size_t)(row + e) * N + col]);
  *reinterpret_cast<bf16x8*>(dst + (size_t)u * 8) = ov;
}

// ---- K1: 32-row tile; depth-1 B prefetch (r6 verbatim) --------------------
__global__ __launch_bounds__(256, 4) void k1_encode(
    const float* __restrict__ obs, const float* __restrict__ hin,
    const float* __restrict__ Ws, const float* __restrict__ bs,
    const float* __restrict__ Wv, const float* __restrict__ bv,
    const short* __restrict__ wgp, const short* __restrict__ wgab,
    short* __restrict__ hpack, float* __restrict__ ha1, float* __restrict__ ha2)
{
  __shared__ __align__(16) short comb[32][584];
  __shared__ float obs_s[32][4];
  const int t = threadIdx.x;
  const int xcd = blockIdx.x & 7, ib = blockIdx.x >> 3;
  const int workid = xcd * 256 + ib;
  const int r0 = workid * 32;

  if (t < 128) obs_s[t >> 2][t & 3] = obs[(size_t)(r0 + (t >> 2)) * 5 + 1 + (t & 3)];
#pragma unroll
  for (int jj = 0; jj < 2; ++jj) {
    const int f = jj * 1024 + t * 4;
    const int row = f >> 6, c = f & 63;
    const float4 v = *reinterpret_cast<const float4*>(hin + (size_t)r0 * 64 + f);
    short4 o;
    o.x = f2bf(v.x); o.y = f2bf(v.y); o.z = f2bf(v.z); o.w = f2bf(v.w);
    *reinterpret_cast<short4*>(&comb[row][512 + c]) = o;
  }
  const float ws0 = Ws[t], ws1 = Ws[256 + t], bsv = bs[t];
  const float wv0 = Wv[t], wv1 = Wv[256 + t], bvv = bv[t];
  __syncthreads();
  for (int r = 0; r < 32; ++r) {
    const float o1 = obs_s[r][0], o2 = obs_s[r][1], o3 = obs_s[r][2], o4 = obs_s[r][3];
    const float sv = fmaf(o2, ws1, fmaf(o1, ws0, bsv));
    comb[r][t] = f2bf(fmaxf(sv, 0.f));
    const float vv = fmaf(o4, wv1, fmaf(o3, wv0, bvv));
    comb[r][256 + t] = f2bf(fmaxf(vv, 0.f));
  }
  __syncthreads();

  const int w = t >> 6, lane = t & 63, lo = lane & 15, hq = lane >> 4;
  f32x4 acc[2][4];
  f32x4 accE[2];
#pragma unroll
  for (int rt = 0; rt < 2; ++rt) {
    accE[rt] = (f32x4){0.f, 0.f, 0.f, 0.f};
#pragma unroll
    for (int ct = 0; ct < 4; ++ct) acc[rt][ct] = (f32x4){0.f, 0.f, 0.f, 0.f};
  }

  const short* wB = wgp + ((size_t)(w*4)*64 + lane)*8;
  bf16x8 bb[4];
#pragma unroll
  for (int ct = 0; ct < 4; ++ct)
    bb[ct] = *reinterpret_cast<const bf16x8*>(wB + ct*512);

#pragma unroll
  for (int ks = 0; ks < 18; ++ks) {
    bf16x8 bn[4];
    if (ks < 17) {
#pragma unroll
      for (int ct = 0; ct < 4; ++ct)
        bn[ct] = *reinterpret_cast<const bf16x8*>(wB + (ks+1)*8192 + ct*512);
    }
    bf16x8 a[2];
#pragma unroll
    for (int rt = 0; rt < 2; ++rt)
      a[rt] = *reinterpret_cast<const bf16x8*>(&comb[rt*16 + lo][ks*32 + hq*8]);
#pragma unroll
    for (int rt = 0; rt < 2; ++rt)
#pragma unroll
      for (int ct = 0; ct < 4; ++ct)
        acc[rt][ct] = __builtin_amdgcn_mfma_f32_16x16x32_bf16(a[rt], bb[ct], acc[rt][ct], 0, 0, 0);
    if (w == 0) {
      bf16x8 be;
      if (lo < 2)
        be = *reinterpret_cast<const bf16x8*>(wgab + ((ks*2 + lo)*4 + hq)*8);
      else
        be = (bf16x8){0,0,0,0,0,0,0,0};
#pragma unroll
      for (int rt = 0; rt < 2; ++rt)
        accE[rt] = __builtin_amdgcn_mfma_f32_16x16x32_bf16(a[rt], be, accE[rt], 0, 0, 0);
    }
    if (ks < 17) {
#pragma unroll
      for (int ct = 0; ct < 4; ++ct) bb[ct] = bn[ct];
    }
  }
  if (w == 0 && lo < 2) {
    float* dst = (lo == 0) ? ha1 : ha2;
#pragma unroll
    for (int rt = 0; rt < 2; ++rt)
#pragma unroll
      for (int q = 0; q < 4; ++q)
        dst[r0 + rt*16 + hq*4 + q] = accE[rt][q];
  }
  __syncthreads();

  short* pimg = reinterpret_cast<short*>(&comb[0][0]);
#pragma unroll
  for (int rt = 0; rt < 2; ++rt)
#pragma unroll
    for (int ct = 0; ct < 4; ++ct) {
      const int base = (((w*4 + ct)*64) + (rt*2 + (hq>>1))*16 + lo)*8 + (hq&1)*4;
      short4 val;
      val.x = f2bf(acc[rt][ct][0]); val.y = f2bf(acc[rt][ct][1]);
      val.z = f2bf(acc[rt][ct][2]); val.w = f2bf(acc[rt][ct][3]);
      *reinterpret_cast<short4*>(pimg + base) = val;
    }
  __syncthreads();

  short* dst = hpack + (size_t)workid * 8192;
#pragma unroll
  for (int j = 0; j < 4; ++j)
    *reinterpret_cast<bf16x8*>(dst + j*2048 + t*8) =
        *reinterpret_cast<const bf16x8*>(pimg + j*2048 + t*8);
}

// ---- K23: 64-row tile, 4 blocks/CU (r6 verbatim) ---------------------------
__global__ __launch_bounds__(256, 4) void k23_attn_fc1(
    const float* __restrict__ ha1g, const float* __restrict__ ha2g,
    const short* __restrict__ hpack, const float* __restrict__ obs,
    const float* __restrict__ Ws, const float* __restrict__ bs,
    const short* __restrict__ w1p, short* __restrict__ y, float* __restrict__ st)
{
  __shared__ __align__(16) short attimg[64][264];
  __shared__ float ws_s[768];
  __shared__ float ha2_s[256];
  __shared__ float ha1_s[64], rd_s[64];
  __shared__ float red[4][64];
  __shared__ float obs_s[64][2];
  const int t = threadIdx.x;
  const int xcd = blockIdx.x & 7, ib = blockIdx.x >> 3;
  const int workid = xcd * 128 + ib;
  const int r0 = workid * 64;
  const int n = r0 >> 8;

  ws_s[t] = Ws[t]; ws_s[256 + t] = Ws[256 + t]; ws_s[512 + t] = bs[t];
  ha2_s[t] = ha2g[n*256 + t];
  if (t < 64) ha1_s[t] = ha1g[r0 + t];
  if (t < 128) obs_s[t >> 1][t & 1] = obs[(size_t)(r0 + (t >> 1)) * 5 + 1 + (t & 1)];
  __syncthreads();

  const int rr = t & 63, seg = t >> 6;
  {
    const float a1 = ha1_s[rr];
    float sum = 0.f;
    for (int c8 = 0; c8 < 8; ++c8) {
      bf16x8 pk;
#pragma unroll
      for (int e = 0; e < 8; ++e) {
        float x = a1 + ha2_s[seg*64 + c8*8 + e];
        x = fmaxf(x, 0.01f * x);
        const float ev = __expf(x);
        sum += ev;
        pk[e] = f2bf(ev);
      }
      *reinterpret_cast<bf16x8*>(&attimg[rr][seg*64 + c8*8]) = pk;
    }
    red[seg][rr] = sum;
  }
  __syncthreads();
  if (t < 64) rd_s[t] = 1.f / (red[0][t] + red[1][t] + red[2][t] + red[3][t]);
  __syncthreads();

  const int w = t >> 6, lane = t & 63, lo = lane & 15, hq = lane >> 4;
  f32x4 acc[4][4];
#pragma unroll
  for (int rt = 0; rt < 4; ++rt)
#pragma unroll
    for (int ct = 0; ct < 4; ++ct) acc[rt][ct] = (f32x4){0.f, 0.f, 0.f, 0.f};

  // MFMA1: h' = att @ h
  {
    const short* bB = hpack + (size_t)n*65536 + ((size_t)(w*4)*64 + lane)*8;
    bf16x8 bb[4];
#pragma unroll
    for (int ct = 0; ct < 4; ++ct) bb[ct] = *reinterpret_cast<const bf16x8*>(bB + ct*512);
    for (int ks = 0; ks < 8; ++ks) {
      bf16x8 bn[4];
      if (ks < 7) {
#pragma unroll
        for (int ct = 0; ct < 4; ++ct)
          bn[ct] = *reinterpret_cast<const bf16x8*>(bB + (ks+1)*8192 + ct*512);
      }
      bf16x8 a[4];
#pragma unroll
      for (int rt = 0; rt < 4; ++rt)
        a[rt] = *reinterpret_cast<const bf16x8*>(&attimg[rt*16 + lo][ks*32 + hq*8]);
#pragma unroll
      for (int rt = 0; rt < 4; ++rt)
#pragma unroll
        for (int ct = 0; ct < 4; ++ct)
          acc[rt][ct] = __builtin_amdgcn_mfma_f32_16x16x32_bf16(a[rt], bb[ct], acc[rt][ct], 0, 0, 0);
      if (ks < 7) {
#pragma unroll
        for (int ct = 0; ct < 4; ++ct) bb[ct] = bn[ct];
      }
    }
  }
  __syncthreads();

#pragma unroll
  for (int rt = 0; rt < 4; ++rt)
#pragma unroll
    for (int q = 0; q < 4; ++q) {
      const int row = rt*16 + hq*4 + q;
      const float sc = rd_s[row];
#pragma unroll
      for (int ct = 0; ct < 4; ++ct)
        attimg[row][w*64 + ct*16 + lo] = f2bf(acc[rt][ct][q] * sc);
    }
  __syncthreads();

  // MFMA2a: y += h' @ W1[0:256]
  f32x4 accY[4][4];
#pragma unroll
  for (int rt = 0; rt < 4; ++rt)
#pragma unroll
    for (int ct = 0; ct < 4; ++ct) accY[rt][ct] = (f32x4){0.f, 0.f, 0.f, 0.f};
  const short* w1B = w1p + ((size_t)(w*4)*64 + lane)*8;
  {
    bf16x8 bb[4];
#pragma unroll
    for (int ct = 0; ct < 4; ++ct) bb[ct] = *reinterpret_cast<const bf16x8*>(w1B + ct*512);
    for (int ks = 0; ks < 8; ++ks) {
      bf16x8 bn[4];
      if (ks < 7) {
#pragma unroll
        for (int ct = 0; ct < 4; ++ct)
          bn[ct] = *reinterpret_cast<const bf16x8*>(w1B + (ks+1)*8192 + ct*512);
      }
      bf16x8 a[4];
#pragma unroll
      for (int rt = 0; rt < 4; ++rt)
        a[rt] = *reinterpret_cast<const bf16x8*>(&attimg[rt*16 + lo][ks*32 + hq*8]);
#pragma unroll
      for (int rt = 0; rt < 4; ++rt)
#pragma unroll
        for (int ct = 0; ct < 4; ++ct)
          accY[rt][ct] = __builtin_amdgcn_mfma_f32_16x16x32_bf16(a[rt], bb[ct], accY[rt][ct], 0, 0, 0);
      if (ks < 7) {
#pragma unroll
        for (int ct = 0; ct < 4; ++ct) bb[ct] = bn[ct];
      }
    }
  }
  __syncthreads();

  // build se into attimg
  {
    const float o1 = obs_s[rr][0], o2 = obs_s[rr][1];
    for (int c8 = 0; c8 < 8; ++c8) {
      const int c = seg*64 + c8*8;
      bf16x8 pk;
#pragma unroll
      for (int e = 0; e < 8; ++e) {
        const float sv = fmaf(o2, ws_s[256 + c + e], fmaf(o1, ws_s[c + e], ws_s[512 + c + e]));
        pk[e] = f2bf(fmaxf(sv, 0.f));
      }
      *reinterpret_cast<bf16x8*>(&attimg[rr][c]) = pk;
    }
  }
  __syncthreads();

  // MFMA2b: y += se @ W1[256:512]
  {
    bf16x8 bb[4];
#pragma unroll
    for (int ct = 0; ct < 4; ++ct)
      bb[ct] = *reinterpret_cast<const bf16x8*>(w1B + 8*8192 + ct*512);
    for (int ks = 0; ks < 8; ++ks) {
      bf16x8 bn[4];
      if (ks < 7) {
#pragma unroll
        for (int ct = 0; ct < 4; ++ct)
          bn[ct] = *reinterpret_cast<const bf16x8*>(w1B + (ks+9)*8192 + ct*512);
      }
      bf16x8 a[4];
#pragma unroll
      for (int rt = 0; rt < 4; ++rt)
        a[rt] = *reinterpret_cast<const bf16x8*>(&attimg[rt*16 + lo][ks*32 + hq*8]);
#pragma unroll
      for (int rt = 0; rt < 4; ++rt)
#pragma unroll
        for (int ct = 0; ct < 4; ++ct)
          accY[rt][ct] = __builtin_amdgcn_mfma_f32_16x16x32_bf16(a[rt], bb[ct], accY[rt][ct], 0, 0, 0);
      if (ks < 7) {
#pragma unroll
        for (int ct = 0; ct < 4; ++ct) bb[ct] = bn[ct];
      }
    }
  }

  // BN1 partial sums
  float sm[4] = {0,0,0,0}, ssm[4] = {0,0,0,0};
#pragma unroll
  for (int rt = 0; rt < 4; ++rt)
#pragma unroll
    for (int q = 0; q < 4; ++q)
#pragma unroll
      for (int ct = 0; ct < 4; ++ct) {
        const float v = accY[rt][ct][q];
        sm[ct] += v; ssm[ct] += v * v;
      }
#pragma unroll
  for (int off = 16; off < 64; off <<= 1)
#pragma unroll
    for (int ct = 0; ct < 4; ++ct) {
      sm[ct] += __shfl_xor(sm[ct], off);
      ssm[ct] += __shfl_xor(ssm[ct], off);
    }
  if (hq == 0)
#pragma unroll
    for (int ct = 0; ct < 4; ++ct) {
      const int col = w*64 + ct*16 + lo;
      atomicAdd(&st[col], sm[ct]);
      atomicAdd(&st[256 + col], ssm[ct]);
    }
  __syncthreads();

#pragma unroll
  for (int rt = 0; rt < 4; ++rt)
#pragma unroll
    for (int q = 0; q < 4; ++q) {
      const int row = rt*16 + hq*4 + q;
#pragma unroll
      for (int ct = 0; ct < 4; ++ct)
        attimg[row][w*64 + ct*16 + lo] = f2bf(accY[rt][ct][q]);
    }
  __syncthreads();
  const short* img = &attimg[0][0];
#pragma unroll
  for (int j = 0; j < 8; ++j) {
    const int f = j*2048 + t*8, row = f >> 8, col = f & 255;
    *reinterpret_cast<bf16x8*>(y + (size_t)(r0 + row)*256 + col) =
        *reinterpret_cast<const bf16x8*>(img + row*264 + col);
  }
}

// ---- K5: 64-row tile (r6) + XCD swizzle matching k23's y producer ----------
__global__ __launch_bounds__(256) void k5_z(
    const short* __restrict__ y, const short* __restrict__ w2p,
    const float* __restrict__ g1, const float* __restrict__ be1,
    float* __restrict__ st, short* __restrict__ zb)
{
  __shared__ __align__(16) short xs[64][264];
  __shared__ float sc_s[256], sh_s[256];
  const int t = threadIdx.x;
  // workid w runs on XCD w/128 == XCD of k23 block that wrote y rows w*64
  const int xcd = blockIdx.x & 7, ib = blockIdx.x >> 3;
  const int workid = xcd * 128 + ib;
  const int r0 = workid * 64;
  {
    const float mean = st[t] * (1.f / kNV);
    const float var  = st[256 + t] * (1.f / kNV) - mean * mean;
    const float sc   = g1[t] / sqrtf(var + kEps);
    sc_s[t] = sc; sh_s[t] = be1[t] - mean * sc;
  }
  __syncthreads();
#pragma unroll
  for (int j = 0; j < 8; ++j) {
    const int f = j*2048 + t*8, row = f >> 8, col = f & 255;
    bf16x8 v = *reinterpret_cast<const bf16x8*>(y + (size_t)(r0 + row)*256 + col);
    bf16x8 ov;
#pragma unroll
    for (int e = 0; e < 8; ++e) {
      const float fv = fmaf(bf2f(v[e]), sc_s[col + e], sh_s[col + e]);
      ov[e] = f2bf(fmaxf(fv, 0.f));
    }
    *reinterpret_cast<bf16x8*>(&xs[row][col]) = ov;
  }
  __syncthreads();

  const int w = t >> 6, lane = t & 63, lo = lane & 15, hq = lane >> 4;
  f32x4 acc[4][2];
#pragma unroll
  for (int rt = 0; rt < 4; ++rt)
#pragma unroll
    for (int ct = 0; ct < 2; ++ct) acc[rt][ct] = (f32x4){0.f, 0.f, 0.f, 0.f};

  {
    const short* w2B = w2p + ((size_t)(w*2)*64 + lane)*8;
    bf16x8 bb[2];
#pragma unroll
    for (int ct = 0; ct < 2; ++ct) bb[ct] = *reinterpret_cast<const bf16x8*>(w2B + ct*512);
    for (int ks = 0; ks < 8; ++ks) {
      bf16x8 bn[2];
      if (ks < 7) {
#pragma unroll
        for (int ct = 0; ct < 2; ++ct)
          bn[ct] = *reinterpret_cast<const bf16x8*>(w2B + (ks+1)*4096 + ct*512);
      }
      bf16x8 a[4];
#pragma unroll
      for (int rt = 0; rt < 4; ++rt)
        a[rt] = *reinterpret_cast<const bf16x8*>(&xs[rt*16 + lo][ks*32 + hq*8]);
#pragma unroll
      for (int rt = 0; rt < 4; ++rt)
#pragma unroll
        for (int ct = 0; ct < 2; ++ct)
          acc[rt][ct] = __builtin_amdgcn_mfma_f32_16x16x32_bf16(a[rt], bb[ct], acc[rt][ct], 0, 0, 0);
      if (ks < 7) {
#pragma unroll
        for (int ct = 0; ct < 2; ++ct) bb[ct] = bn[ct];
      }
    }
  }

  float sm[2] = {0,0}, ssm[2] = {0,0};
#pragma unroll
  for (int rt = 0; rt < 4; ++rt)
#pragma unroll
    for (int q = 0; q < 4; ++q)
#pragma unroll
      for (int ct = 0; ct < 2; ++ct) {
        const float v = acc[rt][ct][q];
        sm[ct] += v; ssm[ct] += v * v;
      }
#pragma unroll
  for (int off = 16; off < 64; off <<= 1)
#pragma unroll
    for (int ct = 0; ct < 2; ++ct) {
      sm[ct] += __shfl_xor(sm[ct], off);
      ssm[ct] += __shfl_xor(ssm[ct], off);
    }
  if (hq == 0)
#pragma unroll
    for (int ct = 0; ct < 2; ++ct) {
      const int col = w*32 + ct*16 + lo;
      atomicAdd(&st[1024 + col], sm[ct]);
      atomicAdd(&st[1152 + col], ssm[ct]);
    }
  __syncthreads();

  short* zimg = reinterpret_cast<short*>(&xs[0][0]);
#pragma unroll
  for (int rt = 0; rt < 4; ++rt)
#pragma unroll
    for (int q = 0; q < 4; ++q) {
      const int row = rt*16 + hq*4 + q;
#pragma unroll
      for (int ct = 0; ct < 2; ++ct)
        zimg[row*136 + w*32 + ct*16 + lo] = f2bf(acc[rt][ct][q]);
    }
  __syncthreads();
#pragma unroll
  for (int j = 0; j < 4; ++j) {
    const int f = j*2048 + t*8, row = f >> 7, col = f & 127;
    *reinterpret_cast<bf16x8*>(zb + (size_t)(r0 + row)*128 + col) =
        *reinterpret_cast<const bf16x8*>(zimg + row*136 + col);
  }
}

// ---- K7: out = relu(bn2(z)); XCD swizzle matching k5's zb producer ---------
__global__ __launch_bounds__(256) void k7_out(
    const short* __restrict__ zb, const float* __restrict__ st,
    const float* __restrict__ g2, const float* __restrict__ be2,
    float* __restrict__ out)
{
  __shared__ float sc_s[128], sh_s[128];
  const int t = threadIdx.x;
  // workid v covers zb units v*512 (rows v*32); producer k5 workid v/2 on
  // XCD (v/2)/128 = v/256 -> run v on XCD v/256.
  const int xcd = blockIdx.x & 7, ib = blockIdx.x >> 3;
  const int workid = xcd * 256 + ib;
  if (t < 128) {
    const float mean = st[1024 + t] * (1.f / kNV);
    const float var  = st[1152 + t] * (1.f / kNV) - mean * mean;
    const float sc   = g2[t] / sqrtf(var + kEps);
    sc_s[t] = sc; sh_s[t] = be2[t] - mean * sc;
  }
  __syncthreads();
#pragma unroll
  for (int j = 0; j < 2; ++j) {
    const size_t u = (size_t)workid * 512 + j*256 + t;
    bf16x8 v = *reinterpret_cast<const bf16x8*>(zb + u*8);
    const int col = ((int)u & 15) * 8;
    float4 r0, r1;
    r0.x = fmaxf(fmaf(bf2f(v[0]), sc_s[col+0], sh_s[col+0]), 0.f);
    r0.y = fmaxf(fmaf(bf2f(v[1]), sc_s[col+1], sh_s[col+1]), 0.f);
    r0.z = fmaxf(fmaf(bf2f(v[2]), sc_s[col+2], sh_s[col+2]), 0.f);
    r0.w = fmaxf(fmaf(bf2f(v[3]), sc_s[col+3], sh_s[col+3]), 0.f);
    r1.x = fmaxf(fmaf(bf2f(v[4]), sc_s[col+4], sh_s[col+4]), 0.f);
    r1.y = fmaxf(fmaf(bf2f(v[5]), sc_s[col+5], sh_s[col+5]), 0.f);
    r1.z = fmaxf(fmaf(bf2f(v[6]), sc_s[col+6], sh_s[col+6]), 0.f);
    r1.w = fmaxf(fmaf(bf2f(v[7]), sc_s[col+7], sh_s[col+7]), 0.f);
    *reinterpret_cast<float4*>(out + u*8)     = r0;
    *reinterpret_cast<float4*>(out + u*8 + 4) = r1;
  }
}

} // namespace

extern "C" void kernel_launch(void* const* d_in, const int* in_sizes, int n_in,
                              void* d_out, int out_size, void* d_ws, size_t ws_size,
                              hipStream_t stream) {
  const float* obs = (const float*)d_in[0];
  const float* hin = (const float*)d_in[1];
  const float* Ws  = (const float*)d_in[2];
  const float* bs  = (const float*)d_in[3];
  const float* Wv  = (const float*)d_in[4];
  const float* bv  = (const float*)d_in[5];
  const float* Wg  = (const float*)d_in[6];
  const float* a_w = (const float*)d_in[7];
  const float* W1  = (const float*)d_in[8];
  // d_in[9] = b1: cancels in batchnorm
  const float* g1  = (const float*)d_in[10];
  const float* be1 = (const float*)d_in[11];
  const float* W2  = (const float*)d_in[12];
  // d_in[13] = b2: cancels in batchnorm
  const float* g2  = (const float*)d_in[14];
  const float* be2 = (const float*)d_in[15];

  char* base = (char*)d_ws;
  short* hpack = (short*)(base);                 // 33.5 MB
  short* y     = (short*)(base + 33554432);      // 33.5 MB
  short* zb    = (short*)(base + 67108864);      // 16.8 MB
  float* ha1   = (float*)(base + 83886080);
  float* ha2   = (float*)(base + 84148224);
  float* st    = (float*)(base + 84410368);
  short* wgp   = (short*)(base + 84416512);
  short* w1p   = (short*)(base + 84711424);
  short* w2p   = (short*)(base + 84973568);
  short* wgab  = (short*)(base + 85039104);
  float* out   = (float*)d_out;

  kpack       <<<160,  256, 0, stream>>>(Wg, W1, W2, a_w, wgp, w1p, w2p, wgab, st);
  k1_encode   <<<2048, 256, 0, stream>>>(obs, hin, Ws, bs, Wv, bv, wgp, wgab, hpack, ha1, ha2);
  k23_attn_fc1<<<1024, 256, 0, stream>>>(ha1, ha2, hpack, obs, Ws, bs, w1p, y, st);
  k5_z        <<<1024, 256, 0, stream>>>(y, w2p, g1, be1, st, zb);
  k7_out      <<<2048, 256, 0, stream>>>(zb, st, g2, be2, out);
}